// Round 4
// baseline (134.209 us; speedup 1.0000x reference)
//
#include <hip/hip_runtime.h>
#include <hip/hip_bf16.h>
#include <math.h>

// Problem constants (fixed by setup_inputs): B=4, C=1, H=W=256 -> N=65536/row,
// concat doubles batch to 8 rows. bins = linspace(0,255,256) -> bins[i] == i
// exactly in f32. Values are uniform[0,1)*1275.
//
// exp(-0.5*((v-i)/0.32)^2) underflows f32 to exactly 0.0 for |v-i| > ~4.61,
// so a radius-5 window is numerically identical to the dense reference (same
// nonzero terms, only summation order differs).
//
// Joint entropy via H = log2(S')*(S/S') - (sum v*log2 v)/S', S' = S + EPS;
// EPS-inside-log difference bounded ~1e-5 absolute (negligible vs f32 reorder).
//
// Row semantics: a = [x1s(0..3); x2s(0..3)] -> s1 = row b of a;
//                b-arr = [x2s; x2s]         -> s2 = x2s[b&3].
// hist row r (r=0..7) = marginal pdf of a's row r; pdf_x2 for output row b is
// hist row 4+(b&3).
#define NB     256
#define NSAMP  65536
#define NROWS  8
#define RADIUS 5.0f
#define EPSV   1e-10f

#define JW     8         // joint j-tile width
#define NJT    32        // j tiles (32*8 = 256); grid = 32 x 8 = 256 blocks

// exp(-0.5*(d/0.32)^2) = exp2(EC * d * d), EC = -0.5*log2(e)/0.1024
#define EC     (-7.0444093793406415f)

static __device__ __forceinline__ float scale_val(float x) {
    return x * 255.0f * 5.0f;   // match reference assoc: (x*255)*5
}
static __device__ __forceinline__ float gkern(float d) {
    return exp2f(EC * d * d);
}
static __device__ __forceinline__ float comp4(const float4& v, int e) {
    return e == 0 ? v.x : e == 1 ? v.y : e == 2 ? v.z : v.w;
}

// ---------------------------------------------------------------------------
// Grid (NJT, NROWS) x 1024 threads = 256 blocks -> exactly 1 block/CU.
// Block (jt, b):
//   1. hist partial: chunk jt (2048 samples) of row b       -> hist_part
//   2. joint tile joint[b][:, j0:j0+8] over all s2 samples  -> (S, L) scalars
__global__ __launch_bounds__(1024, 1)
void mi_main_kernel(const float* __restrict__ in1,
                    const float* __restrict__ in2,
                    float* __restrict__ hist_part,   // [8][32][256]
                    float* __restrict__ jpart) {     // [8][32][2]
    const int jt   = blockIdx.x;           // 0..31
    const int b    = blockIdx.y;           // 0..7
    const int tid  = threadIdx.x;          // 0..1023
    const int lane = tid & 63;
    const int wid  = tid >> 6;             // 0..15

    __shared__ float tile[NB][JW];         // 8 KiB joint tile
    __shared__ float sh[NB];               // 1 KiB hist partial
    __shared__ float scr_s[16], scr_l[16];
    float* tf = &tile[0][0];
    tf[tid] = 0.0f;
    tf[tid + 1024] = 0.0f;
    if (tid < NB) sh[tid] = 0.0f;
    __syncthreads();

    const float* s2 = in2 + (b & 3) * NSAMP;
    const float* s1 = (b < 4) ? (in1 + b * NSAMP) : s2;

    // ---- hist partial: 2048 samples, divergent per-lane stamp (cheap) ----
    {
        const float2* hp = reinterpret_cast<const float2*>(s1 + jt * (NSAMP / NJT));
        float2 hv = hp[tid];
        #pragma unroll
        for (int e = 0; e < 2; ++e) {
            float v = scale_val(e ? hv.y : hv.x);
            if (v <= 255.0f + RADIUS) {
                int i0 = (int)ceilf(v - RADIUS);  if (i0 < 0)   i0 = 0;
                int i1 = (int)floorf(v + RADIUS); if (i1 > 255) i1 = 255;
                for (int i = i0; i <= i1; ++i)
                    __hip_atomic_fetch_add(&sh[i], gkern(v - (float)i),
                                           __ATOMIC_RELAXED,
                                           __HIP_MEMORY_SCOPE_WORKGROUP);
            }
        }
    }
    // no sync needed: hist uses sh[], joint uses tile[]; both drained by the
    // __syncthreads() before the store phase.

    // ---- joint scan: wave-cooperative stamping ---------------------------
    const int   j0    = jt * JW;
    const float jlof  = (float)j0 - RADIUS;
    const float jhif  = (float)(j0 + JW - 1) + RADIUS;
    const float v1max = 255.0f + RADIUS;
    const int   u = lane & 7;              // j offset within stamp
    const int   r = lane >> 3;             // i offset within stamp

    const float4* s24 = reinterpret_cast<const float4*>(s2);
    const float4* s14 = reinterpret_cast<const float4*>(s1);

    float4 c2 = s24[tid];
    float4 c1 = (b < 4) ? s14[tid] : c2;
    for (int k = 0; k < NSAMP / (1024 * 4); ++k) {              // 16 iters
        float4 n2, n1;
        if (k < 15) {
            n2 = s24[(k + 1) * 1024 + tid];
            n1 = (b < 4) ? s14[(k + 1) * 1024 + tid] : n2;
        }
        #pragma unroll
        for (int e = 0; e < 4; ++e) {
            float v2 = scale_val(comp4(c2, e));
            float v1 = scale_val(comp4(c1, e));
            bool pass = (v2 >= jlof) & (v2 <= jhif) & (v1 <= v1max);
            unsigned long long m = __ballot(pass);
            while (m) {                    // one whole-wave stamp per event
                int src = __ffsll(m) - 1;
                m &= m - 1;
                float w1 = __shfl(v1, src);
                float w2 = __shfl(v2, src);
                int jlo = (int)ceilf(w2 - RADIUS);  if (jlo < j0)          jlo = j0;
                int jhi = (int)floorf(w2 + RADIUS); if (jhi > j0 + JW - 1) jhi = j0 + JW - 1;
                int ilo = (int)ceilf(w1 - RADIUS);  if (ilo < 0)   ilo = 0;
                int ihi = (int)floorf(w1 + RADIUS); if (ihi > 255) ihi = 255;
                int j = jlo + u;
                bool jok = (j <= jhi);
                float e2 = gkern(w2 - (float)j);   // register-only; safe if unused
                int i = ilo + r;
                if (jok && i <= ihi) {
                    // 64 lanes -> 64 distinct addrs, 2 lanes/bank (free)
                    __hip_atomic_fetch_add(&tile[i][j - j0],
                                           gkern(w1 - (float)i) * e2,
                                           __ATOMIC_RELAXED,
                                           __HIP_MEMORY_SCOPE_WORKGROUP);
                }
                i += 8;                            // window is <= 11 rows
                if (jok && r < 3 && i <= ihi) {
                    __hip_atomic_fetch_add(&tile[i][j - j0],
                                           gkern(w1 - (float)i) * e2,
                                           __ATOMIC_RELAXED,
                                           __HIP_MEMORY_SCOPE_WORKGROUP);
                }
            }
        }
        if (k < 15) { c2 = n2; c1 = n1; }
    }
    __syncthreads();

    // ---- stores: hist partial + tile reduced to (sum v, sum v*log2 v) ----
    if (tid < NB)
        hist_part[(b * NJT + jt) * NB + tid] = sh[tid];

    float s = 0.0f, l = 0.0f;
    {
        float va = tf[tid], vb = tf[tid + 1024];
        if (va > 0.0f) { s += va; l += va * log2f(va); }
        if (vb > 0.0f) { s += vb; l += vb * log2f(vb); }
    }
    #pragma unroll
    for (int off = 32; off > 0; off >>= 1) {
        s += __shfl_down(s, off);
        l += __shfl_down(l, off);
    }
    if (lane == 0) { scr_s[wid] = s; scr_l[wid] = l; }
    __syncthreads();
    if (tid == 0) {
        float S = 0.0f, L = 0.0f;
        #pragma unroll
        for (int w = 0; w < 16; ++w) { S += scr_s[w]; L += scr_l[w]; }
        jpart[(b * NJT + jt) * 2 + 0] = S;
        jpart[(b * NJT + jt) * 2 + 1] = L;
    }
}

// ---------------------------------------------------------------------------
static __device__ __forceinline__ float block_sum256(float v, float* scratch) {
    const int lane = threadIdx.x & 63;
    const int wid  = threadIdx.x >> 6;     // 0..3
    #pragma unroll
    for (int off = 32; off > 0; off >>= 1) v += __shfl_down(v, off);
    __syncthreads();                       // protect scratch from previous use
    if (lane == 0) scratch[wid] = v;
    __syncthreads();
    return scratch[0] + scratch[1] + scratch[2] + scratch[3];
}

__global__ __launch_bounds__(256)
void mi_final_kernel(const float* __restrict__ hist_part,
                     const float* __restrict__ jpart,
                     float* __restrict__ out) {
    const int b   = blockIdx.x;            // 8 blocks
    const int tid = threadIdx.x;           // 0..255, one bin each
    __shared__ float scratch[4];

    float h1 = 0.0f, h2 = 0.0f;
    #pragma unroll
    for (int c = 0; c < NJT; ++c) {        // 32 chunk partials per row
        h1 += hist_part[(b * NJT + c) * NB + tid];
        h2 += hist_part[((4 + (b & 3)) * NJT + c) * NB + tid];
    }
    h1 *= (1.0f / (float)NSAMP);           // pdf = mean over N
    h2 *= (1.0f / (float)NSAMP);
    float n1 = block_sum256(h1, scratch) + EPSV;
    float n2 = block_sum256(h2, scratch) + EPSV;
    float p1 = h1 / n1;
    float p2 = h2 / n2;
    float Hx1 = -block_sum256(p1 * log2f(p1 + EPSV), scratch);
    float Hx2 = -block_sum256(p2 * log2f(p2 + EPSV), scratch);

    float sp = 0.0f, lp = 0.0f;
    if (tid < NJT) {
        sp = jpart[(b * NJT + tid) * 2 + 0];
        lp = jpart[(b * NJT + tid) * 2 + 1];
    }
    float Sj = block_sum256(sp, scratch);
    float Lj = block_sum256(lp, scratch);

    if (tid == 0) {
        float Sp = Sj + EPSV;
        float Hj = log2f(Sp) * (Sj / Sp) - Lj / Sp;
        float mi = Hx1 + Hx2 - Hj;
        out[b] = 2.0f * mi / (Hx1 + Hx2);
    }
}

// ---------------------------------------------------------------------------
extern "C" void kernel_launch(void* const* d_in, const int* in_sizes, int n_in,
                              void* d_out, int out_size, void* d_ws, size_t ws_size,
                              hipStream_t stream) {
    const float* in1 = (const float*)d_in[0];
    const float* in2 = (const float*)d_in[1];
    // d_in[2] = bins: linspace(0,255,256); bins[i] == (float)i exactly.
    float* out       = (float*)d_out;
    float* hist_part = (float*)d_ws;                       // 8*32*256 f32 (256 KB)
    float* jpart     = hist_part + NROWS * NJT * NB;       // 8*32*2   f32

    dim3 mg(NJT, NROWS);                                   // 256 blocks, 1/CU
    mi_main_kernel<<<mg, 1024, 0, stream>>>(in1, in2, hist_part, jpart);

    mi_final_kernel<<<NROWS, 256, 0, stream>>>(hist_part, jpart, out);
}